// Round 1
// baseline (170.706 us; speedup 1.0000x reference)
//
#include <hip/hip_runtime.h>
#include <math.h>

// Marching tets, fully analytic grid. R10 restructure:
//  - Decoupled-lookback scan REPLACED by deterministic 3-phase scan:
//      k_reduce (per-block aggregate, plain stores, no atomics)
//      k_scan   (1 block, scans nb aggregates -> exclusive prefixes + totals)
//      k_vert   (reads its prefix with one uniform load; no spin, no tags)
//    Rationale: ~1073 wave-0s spinning agent-scope atomic loads serialize on
//    the coherent fabric (same pathology as cooperative grid.sync, R6).
//  - k_face: obByte+cubeRank merged into one 8B cubeInfo word (1 gather, not
//    2 dependent ones); full (ob,k) decode pre-resolved into 12KB LDS table
//    {nt:2|pre1:3|pre2:3|6x edge(corner<<3|slot):6b}; corner offsets computed
//    arithmetically (no runtime-indexed local array -> no scratch).
// Kept lessons: no cooperative grid.sync (~100us, R6); tet-per-thread face
// writes (cube-per-thread 4x'd WRITE_SIZE, R6); packed rankWord (R7); no
// memset in launch path (R8) -- all ws arrays fully overwritten in-order each
// iteration, so 0xAA poison is harmless; fast tanh via v_exp_f32 (R9).

typedef unsigned long long ull;

__device__ __forceinline__ float fast_tanh(float x) {
    float e = __expf(2.0f * x);                 // v_exp_f32 path
    return __fdividef(e - 1.0f, e + 1.0f);      // fast divide
}

__device__ __constant__ int c_tri_tab[16][6] = {
    {-1,-1,-1,-1,-1,-1},{1,0,2,-1,-1,-1},{4,0,3,-1,-1,-1},{1,4,2,1,3,4},
    {3,1,5,-1,-1,-1},{2,3,0,2,5,3},{1,4,0,1,5,4},{4,2,5,-1,-1,-1},
    {4,5,2,-1,-1,-1},{4,1,0,4,5,1},{3,2,0,3,5,2},{1,3,5,-1,-1,-1},
    {4,1,2,4,3,1},{3,0,4,-1,-1,-1},{2,0,1,-1,-1,-1},{-1,-1,-1,-1,-1,-1}};
__device__ __constant__ int c_num_tri[16] = {0,1,1,2,1,2,2,1,1,2,2,1,2,1,1,0};
// 6-tet decomposition: cube-corner tuples (corner c = dx<<2|dy<<1|dz)
__device__ __constant__ int c_tc[6][4] = {{0,1,3,7},{0,3,2,7},{0,2,6,7},{0,6,4,7},{0,4,5,7},{0,5,1,7}};
// per (tet k, local edge le): (cmin_corner<<3) | offset_slot_j
__device__ __constant__ int c_te[6][6] = {
    {(0<<3)|0,(0<<3)|2,(0<<3)|6,(1<<3)|1,(1<<3)|5,(3<<3)|3},
    {(0<<3)|2,(0<<3)|1,(0<<3)|6,(2<<3)|0,(3<<3)|3,(2<<3)|4},
    {(0<<3)|1,(0<<3)|5,(0<<3)|6,(2<<3)|3,(2<<3)|4,(6<<3)|0},
    {(0<<3)|5,(0<<3)|3,(0<<3)|6,(4<<3)|1,(6<<3)|0,(4<<3)|2},
    {(0<<3)|3,(0<<3)|4,(0<<3)|6,(4<<3)|0,(4<<3)|2,(5<<3)|1},
    {(0<<3)|4,(0<<3)|0,(0<<3)|6,(1<<3)|3,(5<<3)|1,(1<<3)|5}};

// ---------------------------------------------------------------------------
// Phase 1: per-block aggregate (edgeCnt:20b<<40 | n1:20b<<20 | n2:20b).
// Plain stores; consumed by k_scan in the next dispatch (stream-ordered).
__global__ void k_reduce(const float* __restrict__ level, int NV, int r1,
                         ull* __restrict__ stateA) {
    int b = blockIdx.x;
    int v = b * 256 + threadIdx.x;
    int R = r1 - 1, rsq = r1 * r1;
    bool valid = v < NV;
    float la = valid ? level[v] : 0.f;
    bool occv = valid && (la > 0.f);

    int flags = 0, n1 = 0, n2 = 0;
    if (valid) {
        int x = v / rsq; int rem = v - x * rsq; int y = rem / r1; int z = rem - y * r1;
        bool bx = x < R, by = y < R, bz = z < R;
        bool interior = bx && by && bz;
        bool inb[7] = {bz, by, by && bz, bx, bx && bz, bx && by, interior};
        int deltas[7] = {1, r1, r1 + 1, rsq, rsq + 1, rsq + r1, rsq + r1 + 1};
        int ob = occv ? 1 : 0;
        for (int j = 0; j < 7; j++) {
            float l = inb[j] ? level[v + deltas[j]] : 0.f;
            bool o = inb[j] && (l > 0.f);
            ob |= (o ? 1 : 0) << (j + 1);
            if (inb[j] && (o != occv)) flags |= 1 << j;
        }
        if (interior) {
            for (int k = 0; k < 6; k++) {
                int ti = ((ob >> c_tc[k][0]) & 1) | (((ob >> c_tc[k][1]) & 1) << 1)
                       | (((ob >> c_tc[k][2]) & 1) << 2) | (((ob >> c_tc[k][3]) & 1) << 3);
                int n = c_num_tri[ti];
                n1 += (n == 1); n2 += (n == 2);
            }
        }
    }
    int cnt = __popc(flags);
    int pk = n1 | (n2 << 16);
    for (int o = 1; o < 64; o <<= 1) { cnt += __shfl_xor(cnt, o); pk += __shfl_xor(pk, o); }
    __shared__ int sE[4], sT[4];
    int lane = threadIdx.x & 63, wv = threadIdx.x >> 6;
    if (lane == 0) { sE[wv] = cnt; sT[wv] = pk; }
    __syncthreads();
    if (threadIdx.x == 0) {
        int eb = sE[0] + sE[1] + sE[2] + sE[3];
        int tb = sT[0] + sT[1] + sT[2] + sT[3];
        stateA[b] = ((ull)eb << 40) | ((ull)(tb & 0xffff) << 20) | (ull)(tb >> 16);
    }
}

// ---------------------------------------------------------------------------
// Phase 2: one block scans all nb aggregates -> exclusive prefixes + totals.
// Packed 20-bit fields sum without cross-field carry (M,N1,N2 < 2^20).
__global__ __launch_bounds__(1024) void k_scan(int nb, const ull* __restrict__ stateA,
                                               ull* __restrict__ prefS,
                                               int* __restrict__ totals) {
    __shared__ ull wTot[16], wOff[16];
    __shared__ ull carrySh;
    int tid = threadIdx.x, lane = tid & 63, wv = tid >> 6;
    ull carry = 0;
    int rounds = (nb + 1023) >> 10;
    for (int r = 0; r < rounds; r++) {
        int i = (r << 10) + tid;
        ull a = (i < nb) ? stateA[i] : 0ull;
        ull incl = a;
        for (int o = 1; o < 64; o <<= 1) {
            ull t = (ull)__shfl_up((long long)incl, o);
            if (lane >= o) incl += t;
        }
        if (lane == 63) wTot[wv] = incl;
        __syncthreads();
        if (tid == 0) {
            ull s = 0;
            for (int k = 0; k < 16; k++) { ull t = wTot[k]; wOff[k] = s; s += t; }
            carrySh = s;
        }
        __syncthreads();
        ull excl = carry + wOff[wv] + (incl - a);
        if (i < nb) prefS[i] = excl;
        if (i == nb - 1) {
            ull inc = excl + a;
            totals[0] = (int)((inc >> 40) & 0xFFFFF);  // M
            totals[1] = (int)((inc >> 20) & 0xFFFFF);  // N1
            totals[2] = (int)(inc & 0xFFFFF);          // N2
        }
        carry += carrySh;
        __syncthreads();
    }
}

// ---------------------------------------------------------------------------
// Phase 3: verts + rankWord + cubeInfo. Prefix read with one uniform load.
// cubeInfo word: ob:8 | cubeRank1:20<<8 | cubeRank2:20<<28.
__global__ void k_vert(const float* __restrict__ level, const float* __restrict__ deform,
                       int NV, int r1, float invR,
                       const ull* __restrict__ prefS,
                       unsigned* __restrict__ rankWord, ull* __restrict__ cubeInfo,
                       float* __restrict__ out) {
    int b = blockIdx.x;
    int v = b * 256 + threadIdx.x;
    int R = r1 - 1, rsq = r1 * r1;
    bool valid = v < NV;
    float la = valid ? level[v] : 0.f;
    bool occv = valid && (la > 0.f);

    int x = 0, y = 0, z = 0, flags = 0, n1 = 0, n2 = 0, cidx = 0, ob = 0;
    bool interior = false;
    float lb[7];
    if (valid) {
        x = v / rsq; int rem = v - x * rsq; y = rem / r1; z = rem - y * r1;
        bool bx = x < R, by = y < R, bz = z < R;
        interior = bx && by && bz;
        bool inb[7] = {bz, by, by && bz, bx, bx && bz, bx && by, interior};
        int deltas[7] = {1, r1, r1 + 1, rsq, rsq + 1, rsq + r1, rsq + r1 + 1};
        ob = occv ? 1 : 0;
        for (int j = 0; j < 7; j++) {
            float l = inb[j] ? level[v + deltas[j]] : 0.f;
            lb[j] = l;
            bool o = inb[j] && (l > 0.f);
            ob |= (o ? 1 : 0) << (j + 1);
            if (inb[j] && (o != occv)) flags |= 1 << j;
        }
        if (interior) {
            cidx = ((x * R) + y) * R + z;
            for (int k = 0; k < 6; k++) {
                int ti = ((ob >> c_tc[k][0]) & 1) | (((ob >> c_tc[k][1]) & 1) << 1)
                       | (((ob >> c_tc[k][2]) & 1) << 2) | (((ob >> c_tc[k][3]) & 1) << 3);
                int n = c_num_tri[ti];
                n1 += (n == 1); n2 += (n == 2);
            }
        }
    }
    int cnt = __popc(flags);
    int pk = n1 | (n2 << 16);
    int lane = threadIdx.x & 63, wv = threadIdx.x >> 6;
    int inclE = cnt, inclT = pk;
    for (int o = 1; o < 64; o <<= 1) {
        int tE = __shfl_up(inclE, o);
        int tT = __shfl_up(inclT, o);
        if (lane >= o) { inclE += tE; inclT += tT; }
    }
    __shared__ int wE[4], wT[4];
    if (lane == 63) { wE[wv] = inclE; wT[wv] = inclT; }
    __syncthreads();

    ull ex = prefS[b];                      // uniform -> scalar load, no spin
    int exclE = (int)((ex >> 40) & 0xFFFFF);
    int excl1 = (int)((ex >> 20) & 0xFFFFF);
    int excl2 = (int)(ex & 0xFFFFF);
    int woffE = 0, woffT = 0;
    for (int w2 = 0; w2 < wv; w2++) { woffE += wE[w2]; woffT += wT[w2]; }
    int rank0 = exclE + woffE + inclE - cnt;
    int tExcl = woffT + inclT - pk;
    if (interior)
        cubeInfo[cidx] = (ull)(unsigned)ob
                       | ((ull)(unsigned)(excl1 + (tExcl & 0xffff)) << 8)
                       | ((ull)(unsigned)(excl2 + (tExcl >> 16)) << 28);
    if (valid)
        rankWord[v] = (unsigned)rank0 | ((unsigned)flags << 21);  // coalesced, 4B/vertex

    if (flags) {
        int deltas[7] = {1, r1, r1 + 1, rsq, rsq + 1, rsq + r1, rsq + r1 + 1};
        const int dxs[7] = {0, 0, 0, 1, 1, 1, 1};
        const int dys[7] = {0, 1, 1, 0, 0, 1, 1};
        const int dzs[7] = {1, 0, 1, 0, 1, 0, 1};
        float pax = x * invR + fast_tanh(deform[3 * v])     * invR;
        float pay = y * invR + fast_tanh(deform[3 * v + 1]) * invR;
        float paz = z * invR + fast_tanh(deform[3 * v + 2]) * invR;
        int r = rank0;
        for (int j = 0; j < 7; j++) {
            if (!((flags >> j) & 1)) continue;
            int bb = v + deltas[j];
            float lbv = lb[j];
            float inv = __fdividef(1.0f, la - lbv);
            float w0 = -lbv * inv;
            float w1f = la * inv;
            float pbx = (x + dxs[j]) * invR + fast_tanh(deform[3 * bb])     * invR;
            float pby = (y + dys[j]) * invR + fast_tanh(deform[3 * bb + 1]) * invR;
            float pbz = (z + dzs[j]) * invR + fast_tanh(deform[3 * bb + 2]) * invR;
            out[3 * r]     = pax * w0 + pbx * w1f;
            out[3 * r + 1] = pay * w0 + pby * w1f;
            out[3 * r + 2] = paz * w0 + pbz * w1f;
            r++;
        }
    }
}

// ---------------------------------------------------------------------------
// Phase 4: tet-per-thread faces. One cubeInfo gather; fully pre-resolved LDS
// decode table tab[k*256+ob] = {nt:2|pre1:3|pre2:3|6 x (corner<<3|slot):6b}.
__global__ void k_face(int r1, int NT,
                       const ull* __restrict__ cubeInfo,
                       const unsigned* __restrict__ rankWord,
                       const int* __restrict__ totals,
                       float* __restrict__ out) {
    __shared__ ull tab[1536];
    for (int idx = threadIdx.x; idx < 1536; idx += 256) {
        int ob = idx & 255, k = idx >> 8;
        int ti = ((ob >> c_tc[k][0]) & 1) | (((ob >> c_tc[k][1]) & 1) << 1)
               | (((ob >> c_tc[k][2]) & 1) << 2) | (((ob >> c_tc[k][3]) & 1) << 3);
        int nt = c_num_tri[ti];
        int pre1 = 0, pre2 = 0;
        for (int kk = 0; kk < k; kk++) {
            int tik = ((ob >> c_tc[kk][0]) & 1) | (((ob >> c_tc[kk][1]) & 1) << 1)
                    | (((ob >> c_tc[kk][2]) & 1) << 2) | (((ob >> c_tc[kk][3]) & 1) << 3);
            int m = c_num_tri[tik];
            pre1 += (m == 1); pre2 += (m == 2);
        }
        ull w = (ull)nt | ((ull)pre1 << 2) | ((ull)pre2 << 5);
        for (int e = 0; e < 6; e++) {
            int le = c_tri_tab[ti][e];
            int ce = (le >= 0) ? c_te[k][le] : 0;
            w |= (ull)ce << (8 + 6 * e);
        }
        tab[idx] = w;
    }
    __syncthreads();

    int t = blockIdx.x * 256 + threadIdx.x;
    if (t >= NT) return;
    int c = t / 6;
    int k = t - c * 6;
    ull info = cubeInfo[c];
    ull w = tab[(k << 8) + ((int)info & 255)];
    int nt = (int)w & 3;
    if (nt == 0) return;

    int rsq = r1 * r1, R = r1 - 1, rr = R * R;
    int cx = c / rr; int rem = c - cx * rr; int cy = rem / R; int cz = rem - cy * R;
    int v = (cx * r1 + cy) * r1 + cz;
    int M = totals[0], N1 = totals[1];
    float* faces = out + 3 * (size_t)M;
    ull we = w >> 8;

    // edge rank: ce = corner(3b)<<3 | slot(3b); corner offset arithmetic, no
    // runtime-indexed local array (scratch hazard).
    #define ERANK(ce_)                                                          \
        ({ int ce = (ce_);                                                      \
           int a = v + ((ce >> 5) & 1) * rsq + ((ce >> 4) & 1) * r1 + ((ce >> 3) & 1); \
           unsigned rw = rankWord[a];                                           \
           (float)((int)(rw & 0x1FFFFF) + __popc((rw >> 21) & ((1u << (ce & 7)) - 1u))); })

    if (nt == 1) {
        unsigned r1c = (unsigned)(info >> 8) & 0xFFFFF;
        int pre1 = ((int)w >> 2) & 7;
        size_t base = 3 * (size_t)(r1c + pre1);
        faces[base]     = ERANK((int)(we) & 63);
        faces[base + 1] = ERANK((int)(we >> 6) & 63);
        faces[base + 2] = ERANK((int)(we >> 12) & 63);
    } else {
        unsigned r2c = (unsigned)(info >> 28) & 0xFFFFF;
        int pre2 = ((int)w >> 5) & 7;
        size_t base = 3 * ((size_t)N1 + 2 * (size_t)(r2c + pre2));
        #pragma unroll
        for (int e = 0; e < 6; e++) faces[base + e] = ERANK((int)(we >> (6 * e)) & 63);
    }
    #undef ERANK
}

extern "C" void kernel_launch(void* const* d_in, const int* in_sizes, int n_in,
                              void* d_out, int out_size, void* d_ws, size_t ws_size,
                              hipStream_t stream) {
    const float* level  = (const float*)d_in[0];
    const float* deform = (const float*)d_in[1];
    int NV = in_sizes[0];
    int r1 = 1;
    while ((long long)r1 * r1 * r1 < (long long)NV) r1++;
    int R = r1 - 1;
    float invR = 1.0f / (float)R;

    int nb = (NV + 255) / 256;
    int NC = R * R * R;
    int NT = 6 * NC;
    int nbT = (NT + 255) / 256;

    char* w = (char*)d_ws;
    unsigned* rankWord = (unsigned*)w;
    w += (((size_t)NV * sizeof(unsigned)) + 255) & ~(size_t)255;
    ull* cubeInfo = (ull*)w;
    w += (((size_t)NC * 8) + 255) & ~(size_t)255;
    ull* stateA = (ull*)w;
    w += (((size_t)nb * 8) + 255) & ~(size_t)255;
    ull* prefS = (ull*)w;
    w += (((size_t)nb * 8) + 255) & ~(size_t)255;
    int* totals = (int*)w;

    float* out = (float*)d_out;

    k_reduce<<<nb, 256, 0, stream>>>(level, NV, r1, stateA);
    k_scan<<<1, 1024, 0, stream>>>(nb, stateA, prefS, totals);
    k_vert<<<nb, 256, 0, stream>>>(level, deform, NV, r1, invR, prefS,
                                   rankWord, cubeInfo, out);
    k_face<<<nbT, 256, 0, stream>>>(r1, NT, cubeInfo, rankWord, totals, out);
}

// Round 2
// 129.132 us; speedup vs baseline: 1.3220x; 1.3220x over previous
//
#include <hip/hip_runtime.h>
#include <math.h>

// Marching tets, fully analytic grid. R11:
//  - R10 regression diagnosed: k_face's per-block 1536-entry LDS table build
//    (6 heavy entries/thread, runtime-indexed __constant__ gathers) + 6-way
//    LDS bank conflict from tab[(k<<8)+ob] layout => 69.7us. Fix: build the
//    decode table ONCE in k_scan's idle threads into global dtab[ob*8+k]
//    (16KB, L1-resident), read directly in k_face (no LDS table, no barrier).
//  - NEW theory for ~43us k_vert (10x above traffic roofline): rank-addressed
//    scatter stores. Each store instr's 64 lanes span ~2.7KB (stride ~42B) =>
//    ~43 line-requests/instr instead of ~4, ~20x TA work. Block rank ranges
//    are CONTIGUOUS => stage verts in LDS at local-rank offsets, then copy
//    out dense + coalesced. Same treatment for k_face's two face regions
//    (block bases = thread0's slot values; ends = last valid thread's).
// Kept lessons: deterministic 3-phase scan (no agent-scope spin, R10); no
// cooperative grid.sync (~100us, R6); tet-per-thread face DECODE (cube-per-
// thread 4x'd WRITE_SIZE, R6); packed rankWord (R7); no memset in launch
// path (R8; all ws arrays fully rewritten before read every iteration, incl.
// dtab in k_scan); fast tanh via v_exp_f32 (R9).

typedef unsigned long long ull;

__device__ __forceinline__ float fast_tanh(float x) {
    float e = __expf(2.0f * x);                 // v_exp_f32 path
    return __fdividef(e - 1.0f, e + 1.0f);      // fast divide
}

__device__ __constant__ int c_tri_tab[16][6] = {
    {-1,-1,-1,-1,-1,-1},{1,0,2,-1,-1,-1},{4,0,3,-1,-1,-1},{1,4,2,1,3,4},
    {3,1,5,-1,-1,-1},{2,3,0,2,5,3},{1,4,0,1,5,4},{4,2,5,-1,-1,-1},
    {4,5,2,-1,-1,-1},{4,1,0,4,5,1},{3,2,0,3,5,2},{1,3,5,-1,-1,-1},
    {4,1,2,4,3,1},{3,0,4,-1,-1,-1},{2,0,1,-1,-1,-1},{-1,-1,-1,-1,-1,-1}};
__device__ __constant__ int c_num_tri[16] = {0,1,1,2,1,2,2,1,1,2,2,1,2,1,1,0};
// 6-tet decomposition: cube-corner tuples (corner c = dx<<2|dy<<1|dz)
__device__ __constant__ int c_tc[6][4] = {{0,1,3,7},{0,3,2,7},{0,2,6,7},{0,6,4,7},{0,4,5,7},{0,5,1,7}};
// per (tet k, local edge le): (cmin_corner<<3) | offset_slot_j
__device__ __constant__ int c_te[6][6] = {
    {(0<<3)|0,(0<<3)|2,(0<<3)|6,(1<<3)|1,(1<<3)|5,(3<<3)|3},
    {(0<<3)|2,(0<<3)|1,(0<<3)|6,(2<<3)|0,(3<<3)|3,(2<<3)|4},
    {(0<<3)|1,(0<<3)|5,(0<<3)|6,(2<<3)|3,(2<<3)|4,(6<<3)|0},
    {(0<<3)|5,(0<<3)|3,(0<<3)|6,(4<<3)|1,(6<<3)|0,(4<<3)|2},
    {(0<<3)|3,(0<<3)|4,(0<<3)|6,(4<<3)|0,(4<<3)|2,(5<<3)|1},
    {(0<<3)|4,(0<<3)|0,(0<<3)|6,(1<<3)|3,(5<<3)|1,(1<<3)|5}};

// ---------------------------------------------------------------------------
// Phase 1: per-block aggregate (edgeCnt:20b<<40 | n1:20b<<20 | n2:20b).
__global__ void k_reduce(const float* __restrict__ level, int NV, int r1,
                         ull* __restrict__ stateA) {
    int b = blockIdx.x;
    int v = b * 256 + threadIdx.x;
    int R = r1 - 1, rsq = r1 * r1;
    bool valid = v < NV;
    float la = valid ? level[v] : 0.f;
    bool occv = valid && (la > 0.f);

    int flags = 0, n1 = 0, n2 = 0;
    if (valid) {
        int x = v / rsq; int rem = v - x * rsq; int y = rem / r1; int z = rem - y * r1;
        bool bx = x < R, by = y < R, bz = z < R;
        bool interior = bx && by && bz;
        bool inb[7] = {bz, by, by && bz, bx, bx && bz, bx && by, interior};
        int deltas[7] = {1, r1, r1 + 1, rsq, rsq + 1, rsq + r1, rsq + r1 + 1};
        int ob = occv ? 1 : 0;
        for (int j = 0; j < 7; j++) {
            float l = inb[j] ? level[v + deltas[j]] : 0.f;
            bool o = inb[j] && (l > 0.f);
            ob |= (o ? 1 : 0) << (j + 1);
            if (inb[j] && (o != occv)) flags |= 1 << j;
        }
        if (interior) {
            for (int k = 0; k < 6; k++) {
                int ti = ((ob >> c_tc[k][0]) & 1) | (((ob >> c_tc[k][1]) & 1) << 1)
                       | (((ob >> c_tc[k][2]) & 1) << 2) | (((ob >> c_tc[k][3]) & 1) << 3);
                int n = c_num_tri[ti];
                n1 += (n == 1); n2 += (n == 2);
            }
        }
    }
    int cnt = __popc(flags);
    int pk = n1 | (n2 << 16);
    for (int o = 1; o < 64; o <<= 1) { cnt += __shfl_xor(cnt, o); pk += __shfl_xor(pk, o); }
    __shared__ int sE[4], sT[4];
    int lane = threadIdx.x & 63, wv = threadIdx.x >> 6;
    if (lane == 0) { sE[wv] = cnt; sT[wv] = pk; }
    __syncthreads();
    if (threadIdx.x == 0) {
        int eb = sE[0] + sE[1] + sE[2] + sE[3];
        int tb = sT[0] + sT[1] + sT[2] + sT[3];
        stateA[b] = ((ull)eb << 40) | ((ull)(tb & 0xffff) << 20) | (ull)(tb >> 16);
    }
}

// ---------------------------------------------------------------------------
// Phase 2: one block scans all nb aggregates -> exclusive prefixes + totals.
// Also builds the 2048-entry face decode table ONCE into global dtab
// (layout [ob*8+k] so the 6 lanes of one cube read consecutive 8B words).
// dtab word: nt:2 | pre1:3 | pre2:3 | 6 x (corner<<3|slot):6b at bit 8+6e.
__global__ __launch_bounds__(1024) void k_scan(int nb, const ull* __restrict__ stateA,
                                               ull* __restrict__ prefS,
                                               int* __restrict__ totals,
                                               ull* __restrict__ dtab) {
    for (int idx = threadIdx.x; idx < 2048; idx += 1024) {
        int ob = idx >> 3, k = idx & 7;
        ull w = 0;
        if (k < 6) {
            int ti = ((ob >> c_tc[k][0]) & 1) | (((ob >> c_tc[k][1]) & 1) << 1)
                   | (((ob >> c_tc[k][2]) & 1) << 2) | (((ob >> c_tc[k][3]) & 1) << 3);
            int nt = c_num_tri[ti];
            int pre1 = 0, pre2 = 0;
            for (int kk = 0; kk < k; kk++) {
                int tik = ((ob >> c_tc[kk][0]) & 1) | (((ob >> c_tc[kk][1]) & 1) << 1)
                        | (((ob >> c_tc[kk][2]) & 1) << 2) | (((ob >> c_tc[kk][3]) & 1) << 3);
                int m = c_num_tri[tik];
                pre1 += (m == 1); pre2 += (m == 2);
            }
            w = (ull)nt | ((ull)pre1 << 2) | ((ull)pre2 << 5);
            for (int e = 0; e < 6; e++) {
                int le = c_tri_tab[ti][e];
                int ce = (le >= 0) ? c_te[k][le] : 0;
                w |= (ull)ce << (8 + 6 * e);
            }
        }
        dtab[idx] = w;
    }

    __shared__ ull wTot[16], wOff[16];
    __shared__ ull carrySh;
    int tid = threadIdx.x, lane = tid & 63, wv = tid >> 6;
    ull carry = 0;
    int rounds = (nb + 1023) >> 10;
    for (int r = 0; r < rounds; r++) {
        int i = (r << 10) + tid;
        ull a = (i < nb) ? stateA[i] : 0ull;
        ull incl = a;
        for (int o = 1; o < 64; o <<= 1) {
            ull t = (ull)__shfl_up((long long)incl, o);
            if (lane >= o) incl += t;
        }
        if (lane == 63) wTot[wv] = incl;
        __syncthreads();
        if (tid == 0) {
            ull s = 0;
            for (int k = 0; k < 16; k++) { ull t = wTot[k]; wOff[k] = s; s += t; }
            carrySh = s;
        }
        __syncthreads();
        ull excl = carry + wOff[wv] + (incl - a);
        if (i < nb) prefS[i] = excl;
        if (i == nb - 1) {
            ull inc = excl + a;
            totals[0] = (int)((inc >> 40) & 0xFFFFF);  // M
            totals[1] = (int)((inc >> 20) & 0xFFFFF);  // N1
            totals[2] = (int)(inc & 0xFFFFF);          // N2
        }
        carry += carrySh;
        __syncthreads();
    }
}

// ---------------------------------------------------------------------------
// Phase 3: verts + rankWord + cubeInfo. Vert output staged in LDS at
// local-rank offsets (block's rank range is contiguous), then copied out
// dense+coalesced: rank-strided scatter stores were ~43 line-requests/instr.
// cubeInfo word: ob:8 | cubeRank1:20<<8 | cubeRank2:20<<28.
__global__ void k_vert(const float* __restrict__ level, const float* __restrict__ deform,
                       int NV, int r1, float invR,
                       const ull* __restrict__ prefS,
                       unsigned* __restrict__ rankWord, ull* __restrict__ cubeInfo,
                       float* __restrict__ out) {
    int b = blockIdx.x;
    int v = b * 256 + threadIdx.x;
    int R = r1 - 1, rsq = r1 * r1;
    bool valid = v < NV;
    float la = valid ? level[v] : 0.f;
    bool occv = valid && (la > 0.f);

    int x = 0, y = 0, z = 0, flags = 0, n1 = 0, n2 = 0, cidx = 0, ob = 0;
    bool interior = false;
    float lb[7];
    if (valid) {
        x = v / rsq; int rem = v - x * rsq; y = rem / r1; z = rem - y * r1;
        bool bx = x < R, by = y < R, bz = z < R;
        interior = bx && by && bz;
        bool inb[7] = {bz, by, by && bz, bx, bx && bz, bx && by, interior};
        int deltas[7] = {1, r1, r1 + 1, rsq, rsq + 1, rsq + r1, rsq + r1 + 1};
        ob = occv ? 1 : 0;
        for (int j = 0; j < 7; j++) {
            float l = inb[j] ? level[v + deltas[j]] : 0.f;
            lb[j] = l;
            bool o = inb[j] && (l > 0.f);
            ob |= (o ? 1 : 0) << (j + 1);
            if (inb[j] && (o != occv)) flags |= 1 << j;
        }
        if (interior) {
            cidx = ((x * R) + y) * R + z;
            for (int k = 0; k < 6; k++) {
                int ti = ((ob >> c_tc[k][0]) & 1) | (((ob >> c_tc[k][1]) & 1) << 1)
                       | (((ob >> c_tc[k][2]) & 1) << 2) | (((ob >> c_tc[k][3]) & 1) << 3);
                int n = c_num_tri[ti];
                n1 += (n == 1); n2 += (n == 2);
            }
        }
    }
    int cnt = __popc(flags);
    int pk = n1 | (n2 << 16);
    int lane = threadIdx.x & 63, wv = threadIdx.x >> 6;
    int inclE = cnt, inclT = pk;
    for (int o = 1; o < 64; o <<= 1) {
        int tE = __shfl_up(inclE, o);
        int tT = __shfl_up(inclT, o);
        if (lane >= o) { inclE += tE; inclT += tT; }
    }
    __shared__ int wE[4], wT[4];
    if (lane == 63) { wE[wv] = inclE; wT[wv] = inclT; }
    __syncthreads();

    ull ex = prefS[b];                      // uniform -> scalar load, no spin
    int exclE = (int)((ex >> 40) & 0xFFFFF);
    int excl1 = (int)((ex >> 20) & 0xFFFFF);
    int excl2 = (int)(ex & 0xFFFFF);
    int woffE = 0, woffT = 0;
    for (int w2 = 0; w2 < wv; w2++) { woffE += wE[w2]; woffT += wT[w2]; }
    int rank0 = exclE + woffE + inclE - cnt;
    int tExcl = woffT + inclT - pk;
    if (interior)
        cubeInfo[cidx] = (ull)(unsigned)ob
                       | ((ull)(unsigned)(excl1 + (tExcl & 0xffff)) << 8)
                       | ((ull)(unsigned)(excl2 + (tExcl >> 16)) << 28);
    if (valid)
        rankWord[v] = (unsigned)rank0 | ((unsigned)flags << 21);  // coalesced, 4B/vertex

    __shared__ float ldsV[5376];            // 256 threads * 7 edges * 3 floats
    if (flags) {
        int deltas[7] = {1, r1, r1 + 1, rsq, rsq + 1, rsq + r1, rsq + r1 + 1};
        const int dxs[7] = {0, 0, 0, 1, 1, 1, 1};
        const int dys[7] = {0, 1, 1, 0, 0, 1, 1};
        const int dzs[7] = {1, 0, 1, 0, 1, 0, 1};
        float pax = x * invR + fast_tanh(deform[3 * v])     * invR;
        float pay = y * invR + fast_tanh(deform[3 * v + 1]) * invR;
        float paz = z * invR + fast_tanh(deform[3 * v + 2]) * invR;
        int r = rank0 - exclE;              // local rank within block
        for (int j = 0; j < 7; j++) {
            if (!((flags >> j) & 1)) continue;
            int bb = v + deltas[j];
            float lbv = lb[j];
            float inv = __fdividef(1.0f, la - lbv);
            float w0 = -lbv * inv;
            float w1f = la * inv;
            float pbx = (x + dxs[j]) * invR + fast_tanh(deform[3 * bb])     * invR;
            float pby = (y + dys[j]) * invR + fast_tanh(deform[3 * bb + 1]) * invR;
            float pbz = (z + dzs[j]) * invR + fast_tanh(deform[3 * bb + 2]) * invR;
            ldsV[3 * r]     = pax * w0 + pbx * w1f;
            ldsV[3 * r + 1] = pay * w0 + pby * w1f;
            ldsV[3 * r + 2] = paz * w0 + pbz * w1f;
            r++;
        }
    }
    __syncthreads();
    int eb = wE[0] + wE[1] + wE[2] + wE[3];
    int tot = 3 * eb;
    float* dstV = out + 3 * (size_t)exclE;
    for (int i = threadIdx.x; i < tot; i += 256) dstV[i] = ldsV[i];
}

// ---------------------------------------------------------------------------
// Phase 4: tet-per-thread face DECODE; face output staged in LDS (block's
// rank ranges in both regions are contiguous: bases from thread 0's slots,
// ends from last valid thread's), then copied out dense+coalesced.
__global__ void k_face(int r1, int NT,
                       const ull* __restrict__ cubeInfo,
                       const unsigned* __restrict__ rankWord,
                       const int* __restrict__ totals,
                       const ull* __restrict__ dtab,
                       float* __restrict__ out) {
    int tid = threadIdx.x;
    int t = blockIdx.x * 256 + tid;
    bool act = t < NT;
    int rsq = r1 * r1, R = r1 - 1, rr = R * R;
    ull info = 0, w = 0;
    int k = 0, v = 0, nt = 0;
    if (act) {
        int c = t / 6; k = t - c * 6;
        info = cubeInfo[c];
        w = dtab[(((int)info & 255) << 3) | k];
        nt = (int)w & 3;
        int cx = c / rr; int rem = c - cx * rr; int cy = rem / R; int cz = rem - cy * R;
        v = (cx * r1 + cy) * r1 + cz;
    }
    unsigned slot1 = act ? (unsigned)((info >> 8) & 0xFFFFF) + (unsigned)((w >> 2) & 7) : 0u;
    unsigned slot2 = act ? (unsigned)((info >> 28) & 0xFFFFF) + (unsigned)((w >> 5) & 7) : 0u;

    __shared__ unsigned sB1, sB2, sE1, sE2;
    __shared__ float lds1[768];    // 256 * 3
    __shared__ float lds2[1536];   // 256 * 6
    int lastT = NT - 1 - blockIdx.x * 256; if (lastT > 255) lastT = 255;
    if (tid == 0)     { sB1 = slot1; sB2 = slot2; }
    if (tid == lastT) { sE1 = slot1 + (nt == 1); sE2 = slot2 + (nt == 2); }
    __syncthreads();

    // edge rank: ce = corner(3b)<<3 | slot(3b); arithmetic corner offset.
    #define ERANK(ce_)                                                          \
        ({ int ce = (ce_);                                                      \
           int a = v + ((ce >> 5) & 1) * rsq + ((ce >> 4) & 1) * r1 + ((ce >> 3) & 1); \
           unsigned rw = rankWord[a];                                           \
           (float)((int)(rw & 0x1FFFFF) + __popc((rw >> 21) & ((1u << (ce & 7)) - 1u))); })

    if (act && nt) {
        ull we = w >> 8;
        if (nt == 1) {
            float* d = &lds1[(slot1 - sB1) * 3];
            d[0] = ERANK((int)(we) & 63);
            d[1] = ERANK((int)(we >> 6) & 63);
            d[2] = ERANK((int)(we >> 12) & 63);
        } else {
            float* d = &lds2[(slot2 - sB2) * 6];
            #pragma unroll
            for (int e = 0; e < 6; e++) d[e] = ERANK((int)(we >> (6 * e)) & 63);
        }
    }
    #undef ERANK
    __syncthreads();

    int M = totals[0], N1 = totals[1];
    float* faces = out + 3 * (size_t)M;
    int n1b = (int)(sE1 - sB1), n2b = (int)(sE2 - sB2);
    float* d1 = faces + 3 * (size_t)sB1;
    for (int i = tid; i < 3 * n1b; i += 256) d1[i] = lds1[i];
    float* d2 = faces + 3 * (size_t)N1 + 6 * (size_t)sB2;
    for (int i = tid; i < 6 * n2b; i += 256) d2[i] = lds2[i];
}

extern "C" void kernel_launch(void* const* d_in, const int* in_sizes, int n_in,
                              void* d_out, int out_size, void* d_ws, size_t ws_size,
                              hipStream_t stream) {
    const float* level  = (const float*)d_in[0];
    const float* deform = (const float*)d_in[1];
    int NV = in_sizes[0];
    int r1 = 1;
    while ((long long)r1 * r1 * r1 < (long long)NV) r1++;
    int R = r1 - 1;
    float invR = 1.0f / (float)R;

    int nb = (NV + 255) / 256;
    int NC = R * R * R;
    int NT = 6 * NC;
    int nbT = (NT + 255) / 256;

    char* w = (char*)d_ws;
    unsigned* rankWord = (unsigned*)w;
    w += (((size_t)NV * sizeof(unsigned)) + 255) & ~(size_t)255;
    ull* cubeInfo = (ull*)w;
    w += (((size_t)NC * 8) + 255) & ~(size_t)255;
    ull* stateA = (ull*)w;
    w += (((size_t)nb * 8) + 255) & ~(size_t)255;
    ull* prefS = (ull*)w;
    w += (((size_t)nb * 8) + 255) & ~(size_t)255;
    int* totals = (int*)w;
    w += 256;
    ull* dtab = (ull*)w;   // 2048 * 8B = 16KB decode table, built by k_scan

    float* out = (float*)d_out;

    k_reduce<<<nb, 256, 0, stream>>>(level, NV, r1, stateA);
    k_scan<<<1, 1024, 0, stream>>>(nb, stateA, prefS, totals, dtab);
    k_vert<<<nb, 256, 0, stream>>>(level, deform, NV, r1, invR, prefS,
                                   rankWord, cubeInfo, out);
    k_face<<<nbT, 256, 0, stream>>>(r1, NT, cubeInfo, rankWord, totals, dtab, out);
}

// Round 3
// 117.887 us; speedup vs baseline: 1.4480x; 1.0954x over previous
//
#include <hip/hip_runtime.h>
#include <math.h>

// Marching tets, fully analytic grid. R12: fuse back to 2 kernels.
//  - R10/R11 data REFUTED the R0 lookback-spin theory: fused-lookback k_vert
//    was 43us; the deterministic 3-phase split (k_reduce+k_scan+k_vert) cost
//    ~57us because k_reduce duplicates the whole neighbor-sampling phase and
//    k_scan adds a serial 1-block dispatch + 2 launch gaps. With only ~1073
//    blocks the lookback resolves immediately. => back to R9's fused
//    decoupled-lookback k_vert (tag 01; 0xAA poison and 0x00 both read
//    not-ready), keeping R11's wins:
//      * LDS-staged vert output, dense coalesced copy-out (scatter stores
//        were ~43 line-requests/instr).
//      * global dtab[ob*8+k] decode table (R10's per-block 1536-entry LDS
//        build + 6-way bank-conflict layout cost 69.7us; R11's global table
//        + LDS-staged face writes brought k_face under the 43us visibility
//        floor). dtab now built by k_vert blocks 0..7 (1 entry/thread, after
//        copy-out; stream-ordered before k_face).
// Kept lessons: no cooperative grid.sync (~100us, R6); tet-per-thread face
// DECODE (cube-per-thread 4x'd WRITE_SIZE, R6); packed rankWord (R7); no
// memset in launch path (R8; stateA/prefS tag-validated, dtab fully
// rewritten each iteration); fast tanh via v_exp_f32 (R9).

typedef unsigned long long ull;

#define ST_LD(p)    __hip_atomic_load((p), __ATOMIC_RELAXED, __HIP_MEMORY_SCOPE_AGENT)
#define ST_ST(p,v)  __hip_atomic_store((p), (v), __ATOMIC_RELAXED, __HIP_MEMORY_SCOPE_AGENT)

__device__ __forceinline__ float fast_tanh(float x) {
    float e = __expf(2.0f * x);                 // v_exp_f32 path
    return __fdividef(e - 1.0f, e + 1.0f);      // fast divide
}

__device__ __constant__ int c_tri_tab[16][6] = {
    {-1,-1,-1,-1,-1,-1},{1,0,2,-1,-1,-1},{4,0,3,-1,-1,-1},{1,4,2,1,3,4},
    {3,1,5,-1,-1,-1},{2,3,0,2,5,3},{1,4,0,1,5,4},{4,2,5,-1,-1,-1},
    {4,5,2,-1,-1,-1},{4,1,0,4,5,1},{3,2,0,3,5,2},{1,3,5,-1,-1,-1},
    {4,1,2,4,3,1},{3,0,4,-1,-1,-1},{2,0,1,-1,-1,-1},{-1,-1,-1,-1,-1,-1}};
__device__ __constant__ int c_num_tri[16] = {0,1,1,2,1,2,2,1,1,2,2,1,2,1,1,0};
// 6-tet decomposition: cube-corner tuples (corner c = dx<<2|dy<<1|dz)
__device__ __constant__ int c_tc[6][4] = {{0,1,3,7},{0,3,2,7},{0,2,6,7},{0,6,4,7},{0,4,5,7},{0,5,1,7}};
// per (tet k, local edge le): (cmin_corner<<3) | offset_slot_j
__device__ __constant__ int c_te[6][6] = {
    {(0<<3)|0,(0<<3)|2,(0<<3)|6,(1<<3)|1,(1<<3)|5,(3<<3)|3},
    {(0<<3)|2,(0<<3)|1,(0<<3)|6,(2<<3)|0,(3<<3)|3,(2<<3)|4},
    {(0<<3)|1,(0<<3)|5,(0<<3)|6,(2<<3)|3,(2<<3)|4,(6<<3)|0},
    {(0<<3)|5,(0<<3)|3,(0<<3)|6,(4<<3)|1,(6<<3)|0,(4<<3)|2},
    {(0<<3)|3,(0<<3)|4,(0<<3)|6,(4<<3)|0,(4<<3)|2,(5<<3)|1},
    {(0<<3)|4,(0<<3)|0,(0<<3)|6,(1<<3)|3,(5<<3)|1,(1<<3)|5}};

// state word: [tag:2 = 01 | pad:2 | e:20 | t1:20 | t2:20]
#define TAG      (1ull << 62)
#define PMASK    ((1ull << 60) - 1ull)
#define READY(s) (((s) >> 62) == 1ull)

// ---------------------------------------------------------------------------
// K1: occ flags, self-validating decoupled-lookback scan of (edgeCnt,t1,t2);
// emits LDS-staged verts (dense coalesced copy-out) + packed rankWord
// {flags:7|rank0:21} + cubeInfo {ob:8|rank1:20<<8|rank2:20<<28}; publishes
// totals; blocks 0..7 build the 2048-entry global dtab for K2.
__global__ void k_vert(const float* __restrict__ level, const float* __restrict__ deform,
                       int NV, int r1, float invR,
                       ull* __restrict__ stateA, ull* __restrict__ prefS,
                       unsigned* __restrict__ rankWord, ull* __restrict__ cubeInfo,
                       int* __restrict__ totals, ull* __restrict__ dtab,
                       float* __restrict__ out) {
    int b = blockIdx.x;
    int v = b * 256 + threadIdx.x;
    int R = r1 - 1, rsq = r1 * r1;
    bool valid = v < NV;
    float la = valid ? level[v] : 0.f;
    bool occv = valid && (la > 0.f);

    int x = 0, y = 0, z = 0, flags = 0, n1 = 0, n2 = 0, cidx = 0, ob = 0;
    bool interior = false;
    float lb[7];
    if (valid) {
        x = v / rsq; int rem = v - x * rsq; y = rem / r1; z = rem - y * r1;
        bool bx = x < R, by = y < R, bz = z < R;
        interior = bx && by && bz;
        bool inb[7] = {bz, by, by && bz, bx, bx && bz, bx && by, interior};
        int deltas[7] = {1, r1, r1 + 1, rsq, rsq + 1, rsq + r1, rsq + r1 + 1};
        ob = occv ? 1 : 0;
        for (int j = 0; j < 7; j++) {
            float l = inb[j] ? level[v + deltas[j]] : 0.f;
            lb[j] = l;
            bool o = inb[j] && (l > 0.f);
            ob |= (o ? 1 : 0) << (j + 1);
            if (inb[j] && (o != occv)) flags |= 1 << j;
        }
        if (interior) {
            cidx = ((x * R) + y) * R + z;
            for (int k = 0; k < 6; k++) {
                int ti = ((ob >> c_tc[k][0]) & 1) | (((ob >> c_tc[k][1]) & 1) << 1)
                       | (((ob >> c_tc[k][2]) & 1) << 2) | (((ob >> c_tc[k][3]) & 1) << 3);
                int n = c_num_tri[ti];
                n1 += (n == 1); n2 += (n == 2);
            }
        }
    }
    int cnt = __popc(flags);
    int pk = n1 | (n2 << 16);
    int lane = threadIdx.x & 63, wv = threadIdx.x >> 6;
    int inclE = cnt, inclT = pk;
    for (int o = 1; o < 64; o <<= 1) {
        int tE = __shfl_up(inclE, o);
        int tT = __shfl_up(inclT, o);
        if (lane >= o) { inclE += tE; inclT += tT; }
    }
    __shared__ int wE[4], wT[4];
    __shared__ ull sExcl;
    if (lane == 63) { wE[wv] = inclE; wT[wv] = inclT; }
    __syncthreads();

    if (wv == 0) {
        int eb = 0, t1b = 0, t2b = 0;
        if (lane == 0) {
            eb = wE[0] + wE[1] + wE[2] + wE[3];
            int tb = wT[0] + wT[1] + wT[2] + wT[3];
            t1b = tb & 0xffff; t2b = tb >> 16;
            ST_ST(&stateA[b], TAG | ((ull)eb << 40) | ((ull)t1b << 20) | (ull)t2b);
        }
        ull sum = 0;
        for (int w = 0; 64 * w < b; w++) {
            int i = b - 1 - 64 * w - lane;
            ull pv = (i >= 0) ? ST_LD(&prefS[i]) : 0;
            ull pm = __ballot(i >= 0 && READY(pv));
            int Lp = pm ? (__ffsll((long long)pm) - 1) : 64;
            ull val = 0;
            if (i >= 0 && lane < Lp) {
                ull s;
                do { s = ST_LD(&stateA[i]); } while (!READY(s));
                val = s & PMASK;
            } else if (i >= 0 && lane == Lp) {
                val = pv & PMASK;
            }
            for (int o = 1; o < 64; o <<= 1) val += __shfl_xor(val, o);
            sum += val;
            if (Lp < 64) break;
        }
        if (lane == 0) {
            sExcl = sum;
            ull inc = sum + (((ull)eb << 40) | ((ull)t1b << 20) | (ull)t2b);
            ST_ST(&prefS[b], TAG | inc);
            if (b == (int)gridDim.x - 1) {
                totals[0] = (int)((inc >> 40) & 0xFFFFF);  // M
                totals[1] = (int)((inc >> 20) & 0xFFFFF);  // N1
                totals[2] = (int)(inc & 0xFFFFF);          // N2
            }
        }
    }
    __syncthreads();

    ull ex = sExcl;
    int exclE = (int)((ex >> 40) & 0xFFFFF);
    int excl1 = (int)((ex >> 20) & 0xFFFFF);
    int excl2 = (int)(ex & 0xFFFFF);
    int woffE = 0, woffT = 0;
    for (int w2 = 0; w2 < wv; w2++) { woffE += wE[w2]; woffT += wT[w2]; }
    int rank0 = exclE + woffE + inclE - cnt;
    int tExcl = woffT + inclT - pk;
    if (interior)
        cubeInfo[cidx] = (ull)(unsigned)ob
                       | ((ull)(unsigned)(excl1 + (tExcl & 0xffff)) << 8)
                       | ((ull)(unsigned)(excl2 + (tExcl >> 16)) << 28);
    if (valid)
        rankWord[v] = (unsigned)rank0 | ((unsigned)flags << 21);  // coalesced, 4B/vertex

    __shared__ float ldsV[5376];            // 256 threads * 7 edges * 3 floats
    if (flags) {
        int deltas[7] = {1, r1, r1 + 1, rsq, rsq + 1, rsq + r1, rsq + r1 + 1};
        const int dxs[7] = {0, 0, 0, 1, 1, 1, 1};
        const int dys[7] = {0, 1, 1, 0, 0, 1, 1};
        const int dzs[7] = {1, 0, 1, 0, 1, 0, 1};
        float pax = x * invR + fast_tanh(deform[3 * v])     * invR;
        float pay = y * invR + fast_tanh(deform[3 * v + 1]) * invR;
        float paz = z * invR + fast_tanh(deform[3 * v + 2]) * invR;
        int r = rank0 - exclE;              // local rank within block
        for (int j = 0; j < 7; j++) {
            if (!((flags >> j) & 1)) continue;
            int bb = v + deltas[j];
            float lbv = lb[j];
            float inv = __fdividef(1.0f, la - lbv);
            float w0 = -lbv * inv;
            float w1f = la * inv;
            float pbx = (x + dxs[j]) * invR + fast_tanh(deform[3 * bb])     * invR;
            float pby = (y + dys[j]) * invR + fast_tanh(deform[3 * bb + 1]) * invR;
            float pbz = (z + dzs[j]) * invR + fast_tanh(deform[3 * bb + 2]) * invR;
            ldsV[3 * r]     = pax * w0 + pbx * w1f;
            ldsV[3 * r + 1] = pay * w0 + pby * w1f;
            ldsV[3 * r + 2] = paz * w0 + pbz * w1f;
            r++;
        }
    }
    __syncthreads();
    int eb2 = wE[0] + wE[1] + wE[2] + wE[3];
    int tot = 3 * eb2;
    float* dstV = out + 3 * (size_t)exclE;
    for (int i = threadIdx.x; i < tot; i += 256) dstV[i] = ldsV[i];

    // Blocks 0..7 build the face decode table (1 entry/thread; stream-ordered
    // before k_face). dtab word: nt:2|pre1:3|pre2:3|6 x (corner<<3|slot):6b.
    if (b < 8) {
        int idx = b * 256 + threadIdx.x;    // [0, 2048)
        int obt = idx >> 3, k = idx & 7;
        ull w = 0;
        if (k < 6) {
            int ti = ((obt >> c_tc[k][0]) & 1) | (((obt >> c_tc[k][1]) & 1) << 1)
                   | (((obt >> c_tc[k][2]) & 1) << 2) | (((obt >> c_tc[k][3]) & 1) << 3);
            int nt = c_num_tri[ti];
            int pre1 = 0, pre2 = 0;
            for (int kk = 0; kk < k; kk++) {
                int tik = ((obt >> c_tc[kk][0]) & 1) | (((obt >> c_tc[kk][1]) & 1) << 1)
                        | (((obt >> c_tc[kk][2]) & 1) << 2) | (((obt >> c_tc[kk][3]) & 1) << 3);
                int m = c_num_tri[tik];
                pre1 += (m == 1); pre2 += (m == 2);
            }
            w = (ull)nt | ((ull)pre1 << 2) | ((ull)pre2 << 5);
            for (int e = 0; e < 6; e++) {
                int le = c_tri_tab[ti][e];
                int ce = (le >= 0) ? c_te[k][le] : 0;
                w |= (ull)ce << (8 + 6 * e);
            }
        }
        dtab[idx] = w;
    }
}

// ---------------------------------------------------------------------------
// K2: tet-per-thread face DECODE; face output staged in LDS (block's rank
// ranges in both regions are contiguous: bases from thread 0's slots, ends
// from last valid thread's), then copied out dense+coalesced.
__global__ void k_face(int r1, int NT,
                       const ull* __restrict__ cubeInfo,
                       const unsigned* __restrict__ rankWord,
                       const int* __restrict__ totals,
                       const ull* __restrict__ dtab,
                       float* __restrict__ out) {
    int tid = threadIdx.x;
    int t = blockIdx.x * 256 + tid;
    bool act = t < NT;
    int rsq = r1 * r1, R = r1 - 1, rr = R * R;
    ull info = 0, w = 0;
    int k = 0, v = 0, nt = 0;
    if (act) {
        int c = t / 6; k = t - c * 6;
        info = cubeInfo[c];
        w = dtab[(((int)info & 255) << 3) | k];
        nt = (int)w & 3;
        int cx = c / rr; int rem = c - cx * rr; int cy = rem / R; int cz = rem - cy * R;
        v = (cx * r1 + cy) * r1 + cz;
    }
    unsigned slot1 = act ? (unsigned)((info >> 8) & 0xFFFFF) + (unsigned)((w >> 2) & 7) : 0u;
    unsigned slot2 = act ? (unsigned)((info >> 28) & 0xFFFFF) + (unsigned)((w >> 5) & 7) : 0u;

    __shared__ unsigned sB1, sB2, sE1, sE2;
    __shared__ float lds1[768];    // 256 * 3
    __shared__ float lds2[1536];   // 256 * 6
    int lastT = NT - 1 - blockIdx.x * 256; if (lastT > 255) lastT = 255;
    if (tid == 0)     { sB1 = slot1; sB2 = slot2; }
    if (tid == lastT) { sE1 = slot1 + (nt == 1); sE2 = slot2 + (nt == 2); }
    __syncthreads();

    // edge rank: ce = corner(3b)<<3 | slot(3b); arithmetic corner offset.
    #define ERANK(ce_)                                                          \
        ({ int ce = (ce_);                                                      \
           int a = v + ((ce >> 5) & 1) * rsq + ((ce >> 4) & 1) * r1 + ((ce >> 3) & 1); \
           unsigned rw = rankWord[a];                                           \
           (float)((int)(rw & 0x1FFFFF) + __popc((rw >> 21) & ((1u << (ce & 7)) - 1u))); })

    if (act && nt) {
        ull we = w >> 8;
        if (nt == 1) {
            float* d = &lds1[(slot1 - sB1) * 3];
            d[0] = ERANK((int)(we) & 63);
            d[1] = ERANK((int)(we >> 6) & 63);
            d[2] = ERANK((int)(we >> 12) & 63);
        } else {
            float* d = &lds2[(slot2 - sB2) * 6];
            #pragma unroll
            for (int e = 0; e < 6; e++) d[e] = ERANK((int)(we >> (6 * e)) & 63);
        }
    }
    #undef ERANK
    __syncthreads();

    int M = totals[0], N1 = totals[1];
    float* faces = out + 3 * (size_t)M;
    int n1b = (int)(sE1 - sB1), n2b = (int)(sE2 - sB2);
    float* d1 = faces + 3 * (size_t)sB1;
    for (int i = tid; i < 3 * n1b; i += 256) d1[i] = lds1[i];
    float* d2 = faces + 3 * (size_t)N1 + 6 * (size_t)sB2;
    for (int i = tid; i < 6 * n2b; i += 256) d2[i] = lds2[i];
}

extern "C" void kernel_launch(void* const* d_in, const int* in_sizes, int n_in,
                              void* d_out, int out_size, void* d_ws, size_t ws_size,
                              hipStream_t stream) {
    const float* level  = (const float*)d_in[0];
    const float* deform = (const float*)d_in[1];
    int NV = in_sizes[0];
    int r1 = 1;
    while ((long long)r1 * r1 * r1 < (long long)NV) r1++;
    int R = r1 - 1;
    float invR = 1.0f / (float)R;

    int nb = (NV + 255) / 256;
    int NC = R * R * R;
    int NT = 6 * NC;
    int nbT = (NT + 255) / 256;

    char* w = (char*)d_ws;
    unsigned* rankWord = (unsigned*)w;
    w += (((size_t)NV * sizeof(unsigned)) + 255) & ~(size_t)255;
    ull* cubeInfo = (ull*)w;
    w += (((size_t)NC * 8) + 255) & ~(size_t)255;
    ull* stateA = (ull*)w;
    w += (((size_t)nb * 8) + 255) & ~(size_t)255;
    ull* prefS = (ull*)w;
    w += (((size_t)nb * 8) + 255) & ~(size_t)255;
    int* totals = (int*)w;
    w += 256;
    ull* dtab = (ull*)w;   // 2048 * 8B = 16KB decode table, built by k_vert b<8

    float* out = (float*)d_out;

    k_vert<<<nb, 256, 0, stream>>>(level, deform, NV, r1, invR, stateA, prefS,
                                   rankWord, cubeInfo, totals, dtab, out);
    k_face<<<nbT, 256, 0, stream>>>(r1, NT, cubeInfo, rankWord, totals, dtab, out);
}

// Round 4
// 113.495 us; speedup vs baseline: 1.5041x; 1.0387x over previous
//
#include <hip/hip_runtime.h>
#include <math.h>

// Marching tets, fully analytic grid. R13:
//  - k_vert: chained decoupled-lookback REPLACED by chain-free all-predecessor
//    aggregate sum. With nb=1073 the prefix chain was ~17 serial agent-scope
//    store->poll hops (~8-10us). Now each block sums stateA[0..b-1] directly
//    (publication-only dependency, all-parallel local phases; in-order
//    dispatch => backward waits only => deadlock-free), parallelized over the
//    block's 4 waves (<=5 spin iterations each). prefS deleted.
//  - k_face: tet-per-thread -> cube-per-thread. Loads the cube's 8 corner
//    rankWords ONCE (vs ~27 per-tet gathers), selects the needed corner via
//    7-cndmask register tree (no runtime-indexed array -> no scratch). 6x
//    fewer threads. LDS-staged dense copy-out kept (R6's cube-per-thread
//    WRITE_SIZE blowup was from direct scattered writes; staging removes it).
//    Single 36.9KB staging buffer, region2 packed at offset 3*n1b; grid is
//    exactly 1024 blocks at 4 blocks/CU => full residency.
// Kept lessons: no cooperative grid.sync (~100us, R6); packed rankWord (R7);
// no memset in launch path (R8; stateA tag-validated: 0xAA poison and 0x00
// both read not-ready; dtab fully rewritten each iter); fast tanh via
// v_exp_f32 (R9); LDS-staged vert output (R11); global dtab[ob*8+k] (R11);
// 2-kernel fused structure (R12: 3-phase split cost ~12us extra).

typedef unsigned long long ull;

#define ST_LD(p)    __hip_atomic_load((p), __ATOMIC_RELAXED, __HIP_MEMORY_SCOPE_AGENT)
#define ST_ST(p,v)  __hip_atomic_store((p), (v), __ATOMIC_RELAXED, __HIP_MEMORY_SCOPE_AGENT)

__device__ __forceinline__ float fast_tanh(float x) {
    float e = __expf(2.0f * x);                 // v_exp_f32 path
    return __fdividef(e - 1.0f, e + 1.0f);      // fast divide
}

__device__ __constant__ int c_tri_tab[16][6] = {
    {-1,-1,-1,-1,-1,-1},{1,0,2,-1,-1,-1},{4,0,3,-1,-1,-1},{1,4,2,1,3,4},
    {3,1,5,-1,-1,-1},{2,3,0,2,5,3},{1,4,0,1,5,4},{4,2,5,-1,-1,-1},
    {4,5,2,-1,-1,-1},{4,1,0,4,5,1},{3,2,0,3,5,2},{1,3,5,-1,-1,-1},
    {4,1,2,4,3,1},{3,0,4,-1,-1,-1},{2,0,1,-1,-1,-1},{-1,-1,-1,-1,-1,-1}};
__device__ __constant__ int c_num_tri[16] = {0,1,1,2,1,2,2,1,1,2,2,1,2,1,1,0};
// 6-tet decomposition: cube-corner tuples (corner c = dx<<2|dy<<1|dz)
__device__ __constant__ int c_tc[6][4] = {{0,1,3,7},{0,3,2,7},{0,2,6,7},{0,6,4,7},{0,4,5,7},{0,5,1,7}};
// per (tet k, local edge le): (cmin_corner<<3) | offset_slot_j
__device__ __constant__ int c_te[6][6] = {
    {(0<<3)|0,(0<<3)|2,(0<<3)|6,(1<<3)|1,(1<<3)|5,(3<<3)|3},
    {(0<<3)|2,(0<<3)|1,(0<<3)|6,(2<<3)|0,(3<<3)|3,(2<<3)|4},
    {(0<<3)|1,(0<<3)|5,(0<<3)|6,(2<<3)|3,(2<<3)|4,(6<<3)|0},
    {(0<<3)|5,(0<<3)|3,(0<<3)|6,(4<<3)|1,(6<<3)|0,(4<<3)|2},
    {(0<<3)|3,(0<<3)|4,(0<<3)|6,(4<<3)|0,(4<<3)|2,(5<<3)|1},
    {(0<<3)|4,(0<<3)|0,(0<<3)|6,(1<<3)|3,(5<<3)|1,(1<<3)|5}};

// state word: [tag:2 = 01 | pad:2 | e:20 | t1:20 | t2:20]
#define TAG      (1ull << 62)
#define PMASK    ((1ull << 60) - 1ull)
#define READY(s) (((s) >> 62) == 1ull)

// ---------------------------------------------------------------------------
// K1: occ flags, chain-free scan (each block sums all predecessor aggregates;
// publication-only dependency); emits LDS-staged verts (dense coalesced
// copy-out) + packed rankWord {flags:7|rank0:21} + cubeInfo
// {ob:8|rank1:20<<8|rank2:20<<28}; publishes totals; blocks 0..7 build the
// 2048-entry global dtab for K2.
__global__ void k_vert(const float* __restrict__ level, const float* __restrict__ deform,
                       int NV, int r1, float invR,
                       ull* __restrict__ stateA,
                       unsigned* __restrict__ rankWord, ull* __restrict__ cubeInfo,
                       int* __restrict__ totals, ull* __restrict__ dtab,
                       float* __restrict__ out) {
    int b = blockIdx.x;
    int v = b * 256 + threadIdx.x;
    int R = r1 - 1, rsq = r1 * r1;
    bool valid = v < NV;
    float la = valid ? level[v] : 0.f;
    bool occv = valid && (la > 0.f);

    int x = 0, y = 0, z = 0, flags = 0, n1 = 0, n2 = 0, cidx = 0, ob = 0;
    bool interior = false;
    float lb[7];
    if (valid) {
        x = v / rsq; int rem = v - x * rsq; y = rem / r1; z = rem - y * r1;
        bool bx = x < R, by = y < R, bz = z < R;
        interior = bx && by && bz;
        bool inb[7] = {bz, by, by && bz, bx, bx && bz, bx && by, interior};
        int deltas[7] = {1, r1, r1 + 1, rsq, rsq + 1, rsq + r1, rsq + r1 + 1};
        ob = occv ? 1 : 0;
        for (int j = 0; j < 7; j++) {
            float l = inb[j] ? level[v + deltas[j]] : 0.f;
            lb[j] = l;
            bool o = inb[j] && (l > 0.f);
            ob |= (o ? 1 : 0) << (j + 1);
            if (inb[j] && (o != occv)) flags |= 1 << j;
        }
        if (interior) {
            cidx = ((x * R) + y) * R + z;
            for (int k = 0; k < 6; k++) {
                int ti = ((ob >> c_tc[k][0]) & 1) | (((ob >> c_tc[k][1]) & 1) << 1)
                       | (((ob >> c_tc[k][2]) & 1) << 2) | (((ob >> c_tc[k][3]) & 1) << 3);
                int n = c_num_tri[ti];
                n1 += (n == 1); n2 += (n == 2);
            }
        }
    }
    int cnt = __popc(flags);
    int pk = n1 | (n2 << 16);
    int lane = threadIdx.x & 63, wv = threadIdx.x >> 6;
    int inclE = cnt, inclT = pk;
    for (int o = 1; o < 64; o <<= 1) {
        int tE = __shfl_up(inclE, o);
        int tT = __shfl_up(inclT, o);
        if (lane >= o) { inclE += tE; inclT += tT; }
    }
    __shared__ int wE[4], wT[4];
    __shared__ ull sPart[4];
    if (lane == 63) { wE[wv] = inclE; wT[wv] = inclT; }
    __syncthreads();

    // Publish own aggregate, then all 4 waves sum predecessor aggregates in
    // parallel (wave wv takes chunks 4t+wv). Backward publication-only waits.
    if (threadIdx.x == 0) {
        int eb = wE[0] + wE[1] + wE[2] + wE[3];
        int tb = wT[0] + wT[1] + wT[2] + wT[3];
        ST_ST(&stateA[b], TAG | ((ull)eb << 40) | ((ull)(tb & 0xffff) << 20) | (ull)(tb >> 16));
    }
    ull psum = 0;
    for (int t = 0;; t++) {
        int base = 64 * (4 * t + wv);
        if (base >= b) break;                  // wave-uniform exit
        int i = b - 1 - (base + lane);
        ull s = 0;
        if (i >= 0) {
            do { s = ST_LD(&stateA[i]); } while (!READY(s));
            s &= PMASK;
        }
        psum += s;
    }
    for (int o = 1; o < 64; o <<= 1) psum += __shfl_xor(psum, o);
    if (lane == 0) sPart[wv] = psum;
    __syncthreads();

    ull ex = sPart[0] + sPart[1] + sPart[2] + sPart[3];
    int exclE = (int)((ex >> 40) & 0xFFFFF);
    int excl1 = (int)((ex >> 20) & 0xFFFFF);
    int excl2 = (int)(ex & 0xFFFFF);
    int eb2 = wE[0] + wE[1] + wE[2] + wE[3];
    if (threadIdx.x == 0 && b == (int)gridDim.x - 1) {
        int tb = wT[0] + wT[1] + wT[2] + wT[3];
        ull inc = ex + (((ull)eb2 << 40) | ((ull)(tb & 0xffff) << 20) | (ull)(tb >> 16));
        totals[0] = (int)((inc >> 40) & 0xFFFFF);  // M
        totals[1] = (int)((inc >> 20) & 0xFFFFF);  // N1
        totals[2] = (int)(inc & 0xFFFFF);          // N2
    }
    int woffE = 0, woffT = 0;
    for (int w2 = 0; w2 < wv; w2++) { woffE += wE[w2]; woffT += wT[w2]; }
    int rank0 = exclE + woffE + inclE - cnt;
    int tExcl = woffT + inclT - pk;
    if (interior)
        cubeInfo[cidx] = (ull)(unsigned)ob
                       | ((ull)(unsigned)(excl1 + (tExcl & 0xffff)) << 8)
                       | ((ull)(unsigned)(excl2 + (tExcl >> 16)) << 28);
    if (valid)
        rankWord[v] = (unsigned)rank0 | ((unsigned)flags << 21);  // coalesced, 4B/vertex

    __shared__ float ldsV[5376];            // 256 threads * 7 edges * 3 floats
    if (flags) {
        int deltas[7] = {1, r1, r1 + 1, rsq, rsq + 1, rsq + r1, rsq + r1 + 1};
        const int dxs[7] = {0, 0, 0, 1, 1, 1, 1};
        const int dys[7] = {0, 1, 1, 0, 0, 1, 1};
        const int dzs[7] = {1, 0, 1, 0, 1, 0, 1};
        float pax = x * invR + fast_tanh(deform[3 * v])     * invR;
        float pay = y * invR + fast_tanh(deform[3 * v + 1]) * invR;
        float paz = z * invR + fast_tanh(deform[3 * v + 2]) * invR;
        int r = rank0 - exclE;              // local rank within block
        for (int j = 0; j < 7; j++) {
            if (!((flags >> j) & 1)) continue;
            int bb = v + deltas[j];
            float lbv = lb[j];
            float inv = __fdividef(1.0f, la - lbv);
            float w0 = -lbv * inv;
            float w1f = la * inv;
            float pbx = (x + dxs[j]) * invR + fast_tanh(deform[3 * bb])     * invR;
            float pby = (y + dys[j]) * invR + fast_tanh(deform[3 * bb + 1]) * invR;
            float pbz = (z + dzs[j]) * invR + fast_tanh(deform[3 * bb + 2]) * invR;
            ldsV[3 * r]     = pax * w0 + pbx * w1f;
            ldsV[3 * r + 1] = pay * w0 + pby * w1f;
            ldsV[3 * r + 2] = paz * w0 + pbz * w1f;
            r++;
        }
    }
    __syncthreads();
    int tot = 3 * eb2;
    float* dstV = out + 3 * (size_t)exclE;
    for (int i = threadIdx.x; i < tot; i += 256) dstV[i] = ldsV[i];

    // Blocks 0..7 build the face decode table (1 entry/thread; stream-ordered
    // before k_face). dtab word: nt:2|pre1:3|pre2:3|6 x (corner<<3|slot):6b.
    if (b < 8) {
        int idx = b * 256 + threadIdx.x;    // [0, 2048)
        int obt = idx >> 3, k = idx & 7;
        ull w = 0;
        if (k < 6) {
            int ti = ((obt >> c_tc[k][0]) & 1) | (((obt >> c_tc[k][1]) & 1) << 1)
                   | (((obt >> c_tc[k][2]) & 1) << 2) | (((obt >> c_tc[k][3]) & 1) << 3);
            int nt = c_num_tri[ti];
            int pre1 = 0, pre2 = 0;
            for (int kk = 0; kk < k; kk++) {
                int tik = ((obt >> c_tc[kk][0]) & 1) | (((obt >> c_tc[kk][1]) & 1) << 1)
                        | (((obt >> c_tc[kk][2]) & 1) << 2) | (((obt >> c_tc[kk][3]) & 1) << 3);
                int m = c_num_tri[tik];
                pre1 += (m == 1); pre2 += (m == 2);
            }
            w = (ull)nt | ((ull)pre1 << 2) | ((ull)pre2 << 5);
            for (int e = 0; e < 6; e++) {
                int le = c_tri_tab[ti][e];
                int ce = (le >= 0) ? c_te[k][le] : 0;
                w |= (ull)ce << (8 + 6 * e);
            }
        }
        dtab[idx] = w;
    }
}

// ---------------------------------------------------------------------------
// corner select from 8 registers via cndmask tree (no runtime-indexed array).
__device__ __forceinline__ unsigned sel8(int c, unsigned r0, unsigned r1_, unsigned r2,
                                         unsigned r3, unsigned r4, unsigned r5,
                                         unsigned r6, unsigned r7) {
    unsigned a01 = (c & 1) ? r1_ : r0;
    unsigned a23 = (c & 1) ? r3 : r2;
    unsigned a45 = (c & 1) ? r5 : r4;
    unsigned a67 = (c & 1) ? r7 : r6;
    unsigned lo = (c & 2) ? a23 : a01;
    unsigned hi = (c & 2) ? a67 : a45;
    return (c & 4) ? hi : lo;
}

// ---------------------------------------------------------------------------
// K2: cube-per-thread face decode. One cubeInfo load, 6 dtab words (3x16B),
// 8 corner rankWords ONCE; ~22 edge ranks via cndmask select + popc. Output
// staged in one LDS buffer (region1 at 0, region2 at 3*n1b), dense copy-out.
__global__ void k_face(int r1, int NC,
                       const ull* __restrict__ cubeInfo,
                       const unsigned* __restrict__ rankWord,
                       const int* __restrict__ totals,
                       const ull* __restrict__ dtab,
                       float* __restrict__ out) {
    int tid = threadIdx.x;
    int c = blockIdx.x * 256 + tid;
    bool act = c < NC;
    int rsq = r1 * r1, R = r1 - 1, rr = R * R;

    ull info = 0;
    ull w0 = 0, w1 = 0, w2 = 0, w3 = 0, w4 = 0, w5 = 0;
    unsigned rw0=0,rw1=0,rw2=0,rw3=0,rw4=0,rw5=0,rw6=0,rw7=0;
    if (act) {
        info = cubeInfo[c];
        int ob = (int)info & 255;
        const ull* dp = dtab + (ob << 3);   // 64B-aligned, 6 words used
        ulonglong2 p0 = *reinterpret_cast<const ulonglong2*>(dp);
        ulonglong2 p1 = *reinterpret_cast<const ulonglong2*>(dp + 2);
        ulonglong2 p2 = *reinterpret_cast<const ulonglong2*>(dp + 4);
        w0 = p0.x; w1 = p0.y; w2 = p1.x; w3 = p1.y; w4 = p2.x; w5 = p2.y;
        int cx = c / rr; int rem = c - cx * rr; int cy = rem / R; int cz = rem - cy * R;
        int v = (cx * r1 + cy) * r1 + cz;
        rw0 = rankWord[v];             rw1 = rankWord[v + 1];
        rw2 = rankWord[v + r1];        rw3 = rankWord[v + r1 + 1];
        rw4 = rankWord[v + rsq];       rw5 = rankWord[v + rsq + 1];
        rw6 = rankWord[v + rsq + r1];  rw7 = rankWord[v + rsq + r1 + 1];
    }
    unsigned r1c = (unsigned)((info >> 8) & 0xFFFFF);
    unsigned r2c = (unsigned)((info >> 28) & 0xFFFFF);
    // this cube's triangle counts (from last tet's word: prefix + own)
    int nt5 = (int)w5 & 3;
    int n1c = (((int)w5 >> 2) & 7) + (nt5 == 1);
    int n2c = (((int)w5 >> 5) & 7) + (nt5 == 2);

    __shared__ unsigned sB1, sB2, sE1, sE2;
    __shared__ float ldsF[9216];   // 256 cubes * max 36 floats (3n1+6n2 <= 36)
    int lastT = NC - 1 - blockIdx.x * 256; if (lastT > 255) lastT = 255;
    if (tid == 0)     { sB1 = r1c; sB2 = r2c; }
    if (tid == lastT) { sE1 = r1c + (unsigned)n1c; sE2 = r2c + (unsigned)n2c; }
    __syncthreads();

    int n1b = (int)(sE1 - sB1), n2b = (int)(sE2 - sB2);
    float* Lr1 = ldsF;
    float* Lr2 = ldsF + 3 * n1b;

    #define ERANK(ce_)                                                          \
        ({ int ce = (ce_);                                                      \
           unsigned rw = sel8(ce >> 3, rw0,rw1,rw2,rw3,rw4,rw5,rw6,rw7);        \
           (float)((int)(rw & 0x1FFFFF) + __popc((rw >> 21) & ((1u << (ce & 7)) - 1u))); })

    if (act) {
        int local1 = (int)(r1c - sB1);
        int local2 = (int)(r2c - sB2);
        #define DO_TET(wk) do {                                                 \
            int nt = (int)(wk) & 3;                                             \
            if (nt) {                                                           \
                ull we = (wk) >> 8;                                             \
                if (nt == 1) {                                                  \
                    int s = local1 + (((int)(wk) >> 2) & 7);                    \
                    float* d = &Lr1[3 * s];                                     \
                    d[0] = ERANK((int)(we) & 63);                               \
                    d[1] = ERANK((int)(we >> 6) & 63);                          \
                    d[2] = ERANK((int)(we >> 12) & 63);                         \
                } else {                                                        \
                    int s = local2 + (((int)(wk) >> 5) & 7);                    \
                    float* d = &Lr2[6 * s];                                     \
                    d[0] = ERANK((int)(we) & 63);                               \
                    d[1] = ERANK((int)(we >> 6) & 63);                          \
                    d[2] = ERANK((int)(we >> 12) & 63);                         \
                    d[3] = ERANK((int)(we >> 18) & 63);                         \
                    d[4] = ERANK((int)(we >> 24) & 63);                         \
                    d[5] = ERANK((int)(we >> 30) & 63);                         \
                }                                                               \
            }                                                                   \
        } while (0)
        DO_TET(w0); DO_TET(w1); DO_TET(w2); DO_TET(w3); DO_TET(w4); DO_TET(w5);
        #undef DO_TET
    }
    #undef ERANK
    __syncthreads();

    int M = totals[0], N1 = totals[1];
    float* faces = out + 3 * (size_t)M;
    float* d1 = faces + 3 * (size_t)sB1;
    for (int i = tid; i < 3 * n1b; i += 256) d1[i] = ldsF[i];
    float* d2 = faces + 3 * (size_t)N1 + 6 * (size_t)sB2;
    const float* s2 = ldsF + 3 * n1b;
    for (int i = tid; i < 6 * n2b; i += 256) d2[i] = s2[i];
}

extern "C" void kernel_launch(void* const* d_in, const int* in_sizes, int n_in,
                              void* d_out, int out_size, void* d_ws, size_t ws_size,
                              hipStream_t stream) {
    const float* level  = (const float*)d_in[0];
    const float* deform = (const float*)d_in[1];
    int NV = in_sizes[0];
    int r1 = 1;
    while ((long long)r1 * r1 * r1 < (long long)NV) r1++;
    int R = r1 - 1;
    float invR = 1.0f / (float)R;

    int nb = (NV + 255) / 256;
    int NC = R * R * R;
    int nbC = (NC + 255) / 256;

    char* w = (char*)d_ws;
    unsigned* rankWord = (unsigned*)w;
    w += (((size_t)NV * sizeof(unsigned)) + 255) & ~(size_t)255;
    ull* cubeInfo = (ull*)w;
    w += (((size_t)NC * 8) + 255) & ~(size_t)255;
    ull* stateA = (ull*)w;
    w += (((size_t)nb * 8) + 255) & ~(size_t)255;
    int* totals = (int*)w;
    w += 256;
    ull* dtab = (ull*)w;   // 2048 * 8B = 16KB decode table, built by k_vert b<8

    float* out = (float*)d_out;

    k_vert<<<nb, 256, 0, stream>>>(level, deform, NV, r1, invR, stateA,
                                   rankWord, cubeInfo, totals, dtab, out);
    k_face<<<nbC, 256, 0, stream>>>(r1, NC, cubeInfo, rankWord, totals, dtab, out);
}

// Round 5
// 110.832 us; speedup vs baseline: 1.5402x; 1.0240x over previous
//
#include <hip/hip_runtime.h>
#include <math.h>

// Marching tets, fully analytic grid. R14:
//  - THEORY: kernels total ~65-70us vs ~15us roofline; the only 4x-class
//    mechanism left is rolled-loop scratch (rule #20): k_vert's 7-iter loops
//    (lb[7]/inb[7]/deltas[7]/dxs..) have big bodies (3 tanh + gathers); if
//    hipcc keeps them rolled, all those arrays live in scratch => ~275K
//    threads round-tripping HBM-backed scratch. FIX: #pragma unroll on every
//    7/6-iter loop (arrays become registers).
//  - Emission moved BEFORE the predecessor spin: vert coords need only the
//    LOCAL rank; stage into LDS while other blocks publish aggregates, then
//    spin -> exclE -> rankWord/cubeInfo/copy-out. Hides the spin window.
//  - Magic-mul division (S=46; exact: e*N < 2^33 << 2^46) replaces runtime
//    int division in both kernels.
//  - dtab baked at COMPILE TIME into __constant__ (constexpr ctor); k_vert's
//    per-tet counting uses popc identity (popc 1/3 -> 1 tri, 2 -> 2) so no
//    runtime table; b<8 build tail + 16KB ws buffer deleted.
// Kept lessons: chain-free all-predecessor aggregate sum (R13; chained
// lookback ~17 serial fabric hops); cube-per-thread k_face with 8-corner
// rankWord reuse + cndmask sel8 (R13); LDS-staged dense copy-out for verts
// and faces (R11; scatter stores were ~43 line-req/instr); no cooperative
// grid.sync (~100us, R6); packed rankWord (R7); no memset in launch path
// (R8; stateA tag-validated: 0xAA poison and 0x00 both read not-ready);
// fast tanh via v_exp_f32 (R9); 2-kernel fused structure (R12).

typedef unsigned long long ull;

#define ST_LD(p)    __hip_atomic_load((p), __ATOMIC_RELAXED, __HIP_MEMORY_SCOPE_AGENT)
#define ST_ST(p,v)  __hip_atomic_store((p), (v), __ATOMIC_RELAXED, __HIP_MEMORY_SCOPE_AGENT)

__device__ __forceinline__ float fast_tanh(float x) {
    float e = __expf(2.0f * x);                 // v_exp_f32 path
    return __fdividef(e - 1.0f, e + 1.0f);      // fast divide
}

// exact unsigned division by runtime constant d: M = ceil(2^46/d), host-side.
// Exact for v < 2^20, d < 2^13 (Granlund-Montgomery: e*N < 2^33 < 2^46).
__device__ __forceinline__ int divq(unsigned v, ull M) {
    return (int)(((ull)v * M) >> 46);
}

// ---- compile-time tables (host+device constexpr; device uses folds only) --
constexpr int TT[16][6] = {
    {-1,-1,-1,-1,-1,-1},{1,0,2,-1,-1,-1},{4,0,3,-1,-1,-1},{1,4,2,1,3,4},
    {3,1,5,-1,-1,-1},{2,3,0,2,5,3},{1,4,0,1,5,4},{4,2,5,-1,-1,-1},
    {4,5,2,-1,-1,-1},{4,1,0,4,5,1},{3,2,0,3,5,2},{1,3,5,-1,-1,-1},
    {4,1,2,4,3,1},{3,0,4,-1,-1,-1},{2,0,1,-1,-1,-1},{-1,-1,-1,-1,-1,-1}};
constexpr int NTRI[16] = {0,1,1,2,1,2,2,1,1,2,2,1,2,1,1,0};
constexpr int TC[6][4] = {{0,1,3,7},{0,3,2,7},{0,2,6,7},{0,6,4,7},{0,4,5,7},{0,5,1,7}};
constexpr int TE[6][6] = {
    {(0<<3)|0,(0<<3)|2,(0<<3)|6,(1<<3)|1,(1<<3)|5,(3<<3)|3},
    {(0<<3)|2,(0<<3)|1,(0<<3)|6,(2<<3)|0,(3<<3)|3,(2<<3)|4},
    {(0<<3)|1,(0<<3)|5,(0<<3)|6,(2<<3)|3,(2<<3)|4,(6<<3)|0},
    {(0<<3)|5,(0<<3)|3,(0<<3)|6,(4<<3)|1,(6<<3)|0,(4<<3)|2},
    {(0<<3)|3,(0<<3)|4,(0<<3)|6,(4<<3)|0,(4<<3)|2,(5<<3)|1},
    {(0<<3)|4,(0<<3)|0,(0<<3)|6,(1<<3)|3,(5<<3)|1,(1<<3)|5}};

// dtab word: nt:2 | pre1:3 | pre2:3 | 6 x (corner<<3|slot):6b at bit 8+6e.
struct DTabT { ull w[2048]; };
constexpr DTabT make_dtab() {
    DTabT t{};
    for (int ob = 0; ob < 256; ob++) {
        for (int k = 0; k < 8; k++) {
            ull w = 0;
            if (k < 6) {
                int ti = ((ob >> TC[k][0]) & 1) | (((ob >> TC[k][1]) & 1) << 1)
                       | (((ob >> TC[k][2]) & 1) << 2) | (((ob >> TC[k][3]) & 1) << 3);
                int nt = NTRI[ti];
                int pre1 = 0, pre2 = 0;
                for (int kk = 0; kk < k; kk++) {
                    int tik = ((ob >> TC[kk][0]) & 1) | (((ob >> TC[kk][1]) & 1) << 1)
                            | (((ob >> TC[kk][2]) & 1) << 2) | (((ob >> TC[kk][3]) & 1) << 3);
                    pre1 += (NTRI[tik] == 1); pre2 += (NTRI[tik] == 2);
                }
                w = (ull)nt | ((ull)pre1 << 2) | ((ull)pre2 << 5);
                for (int e = 0; e < 6; e++) {
                    int le = TT[ti][e];
                    int ce = (le >= 0) ? TE[k][le] : 0;
                    w |= (ull)ce << (8 + 6 * e);
                }
            }
            t.w[ob * 8 + k] = w;
        }
    }
    return t;
}
__device__ __constant__ DTabT c_dtab = make_dtab();

// state word: [tag:2 = 01 | pad:2 | e:20 | t1:20 | t2:20]
#define TAG      (1ull << 62)
#define PMASK    ((1ull << 60) - 1ull)
#define READY(s) (((s) >> 62) == 1ull)

// ---------------------------------------------------------------------------
// K1: occ flags; emission at LOCAL rank into LDS BEFORE the predecessor spin
// (hides spin window); chain-free all-predecessor aggregate sum; then
// rankWord {flags:7|rank0:21} + cubeInfo {ob:8|r1:20<<8|r2:20<<28} + dense
// coalesced vert copy-out; last block publishes totals.
__global__ void k_vert(const float* __restrict__ level, const float* __restrict__ deform,
                       int NV, int r1, float invR, ull Mrsq, ull Mr1,
                       ull* __restrict__ stateA,
                       unsigned* __restrict__ rankWord, ull* __restrict__ cubeInfo,
                       int* __restrict__ totals, float* __restrict__ out) {
    int b = blockIdx.x;
    int v = b * 256 + threadIdx.x;
    int R = r1 - 1, rsq = r1 * r1;
    bool valid = v < NV;
    float la = valid ? level[v] : 0.f;
    bool occv = valid && (la > 0.f);

    int x = 0, y = 0, z = 0, flags = 0, n1 = 0, n2 = 0, cidx = 0, ob = 0;
    bool interior = false;
    float lb[7];
    if (valid) {
        x = divq((unsigned)v, Mrsq); int rem = v - x * rsq;
        y = divq((unsigned)rem, Mr1); z = rem - y * r1;
        bool bx = x < R, by = y < R, bz = z < R;
        interior = bx && by && bz;
        bool inb[7] = {bz, by, by && bz, bx, bx && bz, bx && by, interior};
        int deltas[7] = {1, r1, r1 + 1, rsq, rsq + 1, rsq + r1, rsq + r1 + 1};
        ob = occv ? 1 : 0;
        #pragma unroll
        for (int j = 0; j < 7; j++) {
            float l = inb[j] ? level[v + deltas[j]] : 0.f;
            lb[j] = l;
            bool o = inb[j] && (l > 0.f);
            ob |= (o ? 1 : 0) << (j + 1);
            if (inb[j] && (o != occv)) flags |= 1 << j;
        }
        if (interior) {
            cidx = ((x * R) + y) * R + z;
            #pragma unroll
            for (int k = 0; k < 6; k++) {
                int ti = ((ob >> TC[k][0]) & 1) | (((ob >> TC[k][1]) & 1) << 1)
                       | (((ob >> TC[k][2]) & 1) << 2) | (((ob >> TC[k][3]) & 1) << 3);
                int p = __popc(ti);               // popc 1/3 -> 1 tri, 2 -> 2
                n1 += (p == 1) || (p == 3);
                n2 += (p == 2);
            }
        }
    }
    int cnt = __popc(flags);
    int pk = n1 | (n2 << 16);
    int lane = threadIdx.x & 63, wv = threadIdx.x >> 6;
    int inclE = cnt, inclT = pk;
    #pragma unroll
    for (int o = 1; o < 64; o <<= 1) {
        int tE = __shfl_up(inclE, o);
        int tT = __shfl_up(inclT, o);
        if (lane >= o) { inclE += tE; inclT += tT; }
    }
    __shared__ int wE[4], wT[4];
    __shared__ ull sPart[4];
    if (lane == 63) { wE[wv] = inclE; wT[wv] = inclT; }
    __syncthreads();

    // Publish own aggregate as early as possible.
    if (threadIdx.x == 0) {
        int eb = wE[0] + wE[1] + wE[2] + wE[3];
        int tb = wT[0] + wT[1] + wT[2] + wT[3];
        ST_ST(&stateA[b], TAG | ((ull)eb << 40) | ((ull)(tb & 0xffff) << 20) | (ull)(tb >> 16));
    }
    int woffE = 0, woffT = 0;
    for (int w2 = 0; w2 < wv; w2++) { woffE += wE[w2]; woffT += wT[w2]; }
    int localRank = woffE + inclE - cnt;            // block-local edge rank
    int tExcl = woffT + inclT - pk;

    // Emission at LOCAL rank, overlapping predecessors' publication.
    __shared__ float ldsV[5376];            // 256 threads * 7 edges * 3 floats
    if (flags) {
        int deltas[7] = {1, r1, r1 + 1, rsq, rsq + 1, rsq + r1, rsq + r1 + 1};
        const int dxs[7] = {0, 0, 0, 1, 1, 1, 1};
        const int dys[7] = {0, 1, 1, 0, 0, 1, 1};
        const int dzs[7] = {1, 0, 1, 0, 1, 0, 1};
        float pax = x * invR + fast_tanh(deform[3 * v])     * invR;
        float pay = y * invR + fast_tanh(deform[3 * v + 1]) * invR;
        float paz = z * invR + fast_tanh(deform[3 * v + 2]) * invR;
        int r = localRank;
        #pragma unroll
        for (int j = 0; j < 7; j++) {
            if ((flags >> j) & 1) {
                int bb = v + deltas[j];
                float lbv = lb[j];
                float inv = __fdividef(1.0f, la - lbv);
                float w0 = -lbv * inv;
                float w1f = la * inv;
                float pbx = (x + dxs[j]) * invR + fast_tanh(deform[3 * bb])     * invR;
                float pby = (y + dys[j]) * invR + fast_tanh(deform[3 * bb + 1]) * invR;
                float pbz = (z + dzs[j]) * invR + fast_tanh(deform[3 * bb + 2]) * invR;
                ldsV[3 * r]     = pax * w0 + pbx * w1f;
                ldsV[3 * r + 1] = pay * w0 + pby * w1f;
                ldsV[3 * r + 2] = paz * w0 + pbz * w1f;
                r++;
            }
        }
    }

    // Chain-free spin: all 4 waves sum predecessor aggregates in parallel
    // (wave wv takes chunks 4t+wv). Backward publication-only waits.
    ull psum = 0;
    for (int t = 0;; t++) {
        int base = 64 * (4 * t + wv);
        if (base >= b) break;                  // wave-uniform exit
        int i = b - 1 - (base + lane);
        ull s = 0;
        if (i >= 0) {
            do { s = ST_LD(&stateA[i]); } while (!READY(s));
            s &= PMASK;
        }
        psum += s;
    }
    #pragma unroll
    for (int o = 1; o < 64; o <<= 1) psum += __shfl_xor(psum, o);
    if (lane == 0) sPart[wv] = psum;
    __syncthreads();                           // also orders ldsV writes

    ull ex = sPart[0] + sPart[1] + sPart[2] + sPart[3];
    int exclE = (int)((ex >> 40) & 0xFFFFF);
    int excl1 = (int)((ex >> 20) & 0xFFFFF);
    int excl2 = (int)(ex & 0xFFFFF);
    int eb2 = wE[0] + wE[1] + wE[2] + wE[3];
    if (threadIdx.x == 0 && b == (int)gridDim.x - 1) {
        int tb = wT[0] + wT[1] + wT[2] + wT[3];
        ull inc = ex + (((ull)eb2 << 40) | ((ull)(tb & 0xffff) << 20) | (ull)(tb >> 16));
        totals[0] = (int)((inc >> 40) & 0xFFFFF);  // M
        totals[1] = (int)((inc >> 20) & 0xFFFFF);  // N1
        totals[2] = (int)(inc & 0xFFFFF);          // N2
    }
    if (interior)
        cubeInfo[cidx] = (ull)(unsigned)ob
                       | ((ull)(unsigned)(excl1 + (tExcl & 0xffff)) << 8)
                       | ((ull)(unsigned)(excl2 + (tExcl >> 16)) << 28);
    if (valid)
        rankWord[v] = (unsigned)(exclE + localRank) | ((unsigned)flags << 21);

    int tot = 3 * eb2;
    float* dstV = out + 3 * (size_t)exclE;
    for (int i = threadIdx.x; i < tot; i += 256) dstV[i] = ldsV[i];
}

// ---------------------------------------------------------------------------
// corner select from 8 registers via cndmask tree (no runtime-indexed array).
__device__ __forceinline__ unsigned sel8(int c, unsigned r0, unsigned r1_, unsigned r2,
                                         unsigned r3, unsigned r4, unsigned r5,
                                         unsigned r6, unsigned r7) {
    unsigned a01 = (c & 1) ? r1_ : r0;
    unsigned a23 = (c & 1) ? r3 : r2;
    unsigned a45 = (c & 1) ? r5 : r4;
    unsigned a67 = (c & 1) ? r7 : r6;
    unsigned lo = (c & 2) ? a23 : a01;
    unsigned hi = (c & 2) ? a67 : a45;
    return (c & 4) ? hi : lo;
}

// ---------------------------------------------------------------------------
// K2: cube-per-thread face decode. One cubeInfo load, 6 compile-time-constant
// dtab words (3x16B from __constant__), 8 corner rankWords ONCE; edge ranks
// via cndmask select + popc. Output staged in one LDS buffer (region1 at 0,
// region2 at 3*n1b), dense coalesced copy-out.
__global__ void k_face(int r1, int NC, ull Mrr, ull MR,
                       const ull* __restrict__ cubeInfo,
                       const unsigned* __restrict__ rankWord,
                       const int* __restrict__ totals,
                       float* __restrict__ out) {
    int tid = threadIdx.x;
    int c = blockIdx.x * 256 + tid;
    bool act = c < NC;
    int rsq = r1 * r1, R = r1 - 1, rr = R * R;

    ull info = 0;
    ull w0 = 0, w1 = 0, w2 = 0, w3 = 0, w4 = 0, w5 = 0;
    unsigned rw0=0,rw1=0,rw2=0,rw3=0,rw4=0,rw5=0,rw6=0,rw7=0;
    if (act) {
        info = cubeInfo[c];
        int ob = (int)info & 255;
        const ull* dp = &c_dtab.w[ob << 3];   // 64B-aligned, 6 words used
        ulonglong2 p0 = *reinterpret_cast<const ulonglong2*>(dp);
        ulonglong2 p1 = *reinterpret_cast<const ulonglong2*>(dp + 2);
        ulonglong2 p2 = *reinterpret_cast<const ulonglong2*>(dp + 4);
        w0 = p0.x; w1 = p0.y; w2 = p1.x; w3 = p1.y; w4 = p2.x; w5 = p2.y;
        int cx = divq((unsigned)c, Mrr); int rem = c - cx * rr;
        int cy = divq((unsigned)rem, MR); int cz = rem - cy * R;
        int v = (cx * r1 + cy) * r1 + cz;
        rw0 = rankWord[v];             rw1 = rankWord[v + 1];
        rw2 = rankWord[v + r1];        rw3 = rankWord[v + r1 + 1];
        rw4 = rankWord[v + rsq];       rw5 = rankWord[v + rsq + 1];
        rw6 = rankWord[v + rsq + r1];  rw7 = rankWord[v + rsq + r1 + 1];
    }
    unsigned r1c = (unsigned)((info >> 8) & 0xFFFFF);
    unsigned r2c = (unsigned)((info >> 28) & 0xFFFFF);
    // this cube's triangle counts (from last tet's word: prefix + own)
    int nt5 = (int)w5 & 3;
    int n1c = (((int)w5 >> 2) & 7) + (nt5 == 1);
    int n2c = (((int)w5 >> 5) & 7) + (nt5 == 2);

    __shared__ unsigned sB1, sB2, sE1, sE2;
    __shared__ float ldsF[9216];   // 256 cubes * max 36 floats (3n1+6n2 <= 36)
    int lastT = NC - 1 - blockIdx.x * 256; if (lastT > 255) lastT = 255;
    if (tid == 0)     { sB1 = r1c; sB2 = r2c; }
    if (tid == lastT) { sE1 = r1c + (unsigned)n1c; sE2 = r2c + (unsigned)n2c; }
    __syncthreads();

    int n1b = (int)(sE1 - sB1), n2b = (int)(sE2 - sB2);
    float* Lr1 = ldsF;
    float* Lr2 = ldsF + 3 * n1b;

    #define ERANK(ce_)                                                          \
        ({ int ce = (ce_);                                                      \
           unsigned rw = sel8(ce >> 3, rw0,rw1,rw2,rw3,rw4,rw5,rw6,rw7);        \
           (float)((int)(rw & 0x1FFFFF) + __popc((rw >> 21) & ((1u << (ce & 7)) - 1u))); })

    if (act) {
        int local1 = (int)(r1c - sB1);
        int local2 = (int)(r2c - sB2);
        #define DO_TET(wk) do {                                                 \
            int nt = (int)(wk) & 3;                                             \
            if (nt) {                                                           \
                ull we = (wk) >> 8;                                             \
                if (nt == 1) {                                                  \
                    int s = local1 + (((int)(wk) >> 2) & 7);                    \
                    float* d = &Lr1[3 * s];                                     \
                    d[0] = ERANK((int)(we) & 63);                               \
                    d[1] = ERANK((int)(we >> 6) & 63);                          \
                    d[2] = ERANK((int)(we >> 12) & 63);                         \
                } else {                                                        \
                    int s = local2 + (((int)(wk) >> 5) & 7);                    \
                    float* d = &Lr2[6 * s];                                     \
                    d[0] = ERANK((int)(we) & 63);                               \
                    d[1] = ERANK((int)(we >> 6) & 63);                          \
                    d[2] = ERANK((int)(we >> 12) & 63);                         \
                    d[3] = ERANK((int)(we >> 18) & 63);                         \
                    d[4] = ERANK((int)(we >> 24) & 63);                         \
                    d[5] = ERANK((int)(we >> 30) & 63);                         \
                }                                                               \
            }                                                                   \
        } while (0)
        DO_TET(w0); DO_TET(w1); DO_TET(w2); DO_TET(w3); DO_TET(w4); DO_TET(w5);
        #undef DO_TET
    }
    #undef ERANK
    __syncthreads();

    int M = totals[0], N1 = totals[1];
    float* faces = out + 3 * (size_t)M;
    float* d1 = faces + 3 * (size_t)sB1;
    for (int i = tid; i < 3 * n1b; i += 256) d1[i] = ldsF[i];
    float* d2 = faces + 3 * (size_t)N1 + 6 * (size_t)sB2;
    const float* s2 = ldsF + 3 * n1b;
    for (int i = tid; i < 6 * n2b; i += 256) d2[i] = s2[i];
}

extern "C" void kernel_launch(void* const* d_in, const int* in_sizes, int n_in,
                              void* d_out, int out_size, void* d_ws, size_t ws_size,
                              hipStream_t stream) {
    const float* level  = (const float*)d_in[0];
    const float* deform = (const float*)d_in[1];
    int NV = in_sizes[0];
    int r1 = 1;
    while ((long long)r1 * r1 * r1 < (long long)NV) r1++;
    int R = r1 - 1;
    float invR = 1.0f / (float)R;
    int rsq = r1 * r1, rr = R * R;

    // exact-division magics: M = ceil(2^46/d)
    ull Mrsq = ((1ull << 46) + (ull)rsq - 1) / (ull)rsq;
    ull Mr1  = ((1ull << 46) + (ull)r1  - 1) / (ull)r1;
    ull Mrr  = ((1ull << 46) + (ull)rr  - 1) / (ull)rr;
    ull MR   = ((1ull << 46) + (ull)R   - 1) / (ull)R;

    int nb = (NV + 255) / 256;
    int NC = R * R * R;
    int nbC = (NC + 255) / 256;

    char* w = (char*)d_ws;
    unsigned* rankWord = (unsigned*)w;
    w += (((size_t)NV * sizeof(unsigned)) + 255) & ~(size_t)255;
    ull* cubeInfo = (ull*)w;
    w += (((size_t)NC * 8) + 255) & ~(size_t)255;
    ull* stateA = (ull*)w;
    w += (((size_t)nb * 8) + 255) & ~(size_t)255;
    int* totals = (int*)w;

    float* out = (float*)d_out;

    k_vert<<<nb, 256, 0, stream>>>(level, deform, NV, r1, invR, Mrsq, Mr1,
                                   stateA, rankWord, cubeInfo, totals, out);
    k_face<<<nbC, 256, 0, stream>>>(r1, NC, Mrr, MR, cubeInfo, rankWord, totals, out);
}